// Round 1
// baseline (487.419 us; speedup 1.0000x reference)
//
#include <hip/hip_runtime.h>

#define N_NODES 50000
#define N_GRAPHS 512
#define N_EDGES 800000

typedef __attribute__((ext_vector_type(8))) short short8;
typedef __attribute__((ext_vector_type(8))) unsigned short ushort8;
typedef __attribute__((ext_vector_type(4))) float floatx4;

__device__ __forceinline__ float bf2f(unsigned short u) {
    union { unsigned int i; float f; } c;
    c.i = ((unsigned int)u) << 16;
    return c.f;
}
__device__ __forceinline__ unsigned short f2bf(float f) {
    union { float f; unsigned int i; } c;
    c.f = f;
    unsigned int u = c.i;
    return (unsigned short)((u + 0x7fffu + ((u >> 16) & 1u)) >> 16);
}

// async 16B global -> LDS (lane-ordered destination: ldsbase + lane*16)
__device__ __forceinline__ void g2lds16(const unsigned short* g, void* lds) {
    __builtin_amdgcn_global_load_lds(
        (const __attribute__((address_space(1))) void*)g,
        (__attribute__((address_space(3))) void*)lds, 16, 0, 0);
}

// ---------------- fused converts: x (1.6M float4) + W1/W2/W3 (40960) -------
__global__ void convert_all(const float* __restrict__ x, const float* __restrict__ W1,
                            const float* __restrict__ W2, const float* __restrict__ W3,
                            unsigned short* __restrict__ xo, unsigned short* __restrict__ o1,
                            unsigned short* __restrict__ o2, unsigned short* __restrict__ o3) {
    int i = blockIdx.x * blockDim.x + threadIdx.x;  // 0..1640959
    const float* src; unsigned short* dst; int base;
    if (i < 1600000)      { src = x;  dst = xo; base = i; }
    else {
        int j = i - 1600000;
        if (j < 8192)       { src = W1; dst = o1; base = j; }
        else if (j < 24576) { src = W2; dst = o2; base = j - 8192; }
        else if (j < 40960) { src = W3; dst = o3; base = j - 24576; }
        else return;
    }
    float4 v = ((const float4*)src)[base];
    ushort4 o;
    o.x = f2bf(v.x); o.y = f2bf(v.y); o.z = f2bf(v.z); o.w = f2bf(v.w);
    ((ushort4*)dst)[base] = o;
}

// ---------------- CSR build ----------------
__global__ void deg_hist(const int* __restrict__ dst, int* __restrict__ deg) {
    int e = blockIdx.x * blockDim.x + threadIdx.x;
    if (e < N_EDGES) atomicAdd(&deg[dst[e]], 1);
}

__global__ __launch_bounds__(1024) void scan1(const int* __restrict__ deg,
                                              int* __restrict__ rowptr,
                                              int* __restrict__ blocksum) {
    __shared__ int s[1024];
    int t = threadIdx.x;
    int i = blockIdx.x * 1024 + t;
    int v = (i < N_NODES) ? deg[i] : 0;
    s[t] = v;
    __syncthreads();
    for (int off = 1; off < 1024; off <<= 1) {
        int add = (t >= off) ? s[t - off] : 0;
        __syncthreads();
        s[t] += add;
        __syncthreads();
    }
    if (i < N_NODES) rowptr[i] = s[t] - v;  // exclusive
    if (t == 1023) blocksum[blockIdx.x] = s[t];
}

// wave-parallel exclusive scan of block sums (nb <= 64) — replaces the
// previous 1-thread serial loop (~49 dependent global round-trips).
__global__ void scan2(int* __restrict__ blocksum, int nb) {
    int t = threadIdx.x;  // 64 threads, one wave
    int orig = (t < nb) ? blocksum[t] : 0;
    int v = orig;
    for (int off = 1; off < 64; off <<= 1) {
        int u = __shfl_up(v, off, 64);
        if (t >= off) v += u;
    }
    if (t < nb) blocksum[t] = v - orig;  // exclusive
}

__global__ void scan3(int* __restrict__ rowptr, const int* __restrict__ blocksum,
                      int* __restrict__ cursor) {
    int i = blockIdx.x * blockDim.x + threadIdx.x;
    if (i < N_NODES) {
        int v = rowptr[i] + blocksum[i >> 10];
        rowptr[i] = v;
        cursor[i] = v;
    }
    if (i == 0) rowptr[N_NODES] = N_EDGES;
}

__global__ void scatter_csr(const int* __restrict__ src, const int* __restrict__ dst,
                            int* __restrict__ cursor, int* __restrict__ csr) {
    int e = blockIdx.x * blockDim.x + threadIdx.x;
    if (e < N_EDGES) {
        int pos = atomicAdd(&cursor[dst[e]], 1);
        csr[pos] = src[e];
    }
}

// ---- FUSED gather + MFMA GEMM --------------------------------------------
// out = relu((h + sum_neighbors h) @ W[256,K]^T + b) -> bf16
// BM=64 rows/block, BN=256 (full output width), 256 threads = 4 waves.
// Phase 1 (gather): 256/TPN row-groups accumulate rows in registers
// (unroll-8 for in-flight load depth), deposit bf16 A-tile into LDS with
// XOR swizzle byte ^= (row&7)<<4 (row-major [64][K] bf16 would otherwise be
// a 16-way bank conflict on the MFMA ds_read_b128 — G4).
// Phase 2 (GEMM): K-loop BK=32; W staged via global_load_lds with
// source-side swizzle (same slot scheme as the previous gemm_mfma);
// A read straight from the resident LDS tile. Saves the agg_bf round-trip
// (25.6 MB write + 25.6 MB read per layer).
template <int K>
__global__ __launch_bounds__(256, 3) void gin_fused(
    const unsigned short* __restrict__ h, const int* __restrict__ rowptr,
    const int* __restrict__ csr, const unsigned short* __restrict__ W,
    const float* __restrict__ bias, unsigned short* __restrict__ out, int M) {
    constexpr int BM = 64;
    constexpr int AW = K * 2;                 // bytes per A row
    __shared__ unsigned short As[BM * K];     // 32 KB (K=256) / 16 KB (K=128)
    __shared__ short8 Ws[1024];               // 16 KB: 256 W-rows x 32 k

    int tid = threadIdx.x;
    int wave = tid >> 6, lane = tid & 63;
    int lkc = lane >> 4, lr = lane & 15;
    int rowbase = blockIdx.x * BM;

    // ---------------- phase 1: gather into LDS A-tile ----------------
    {
        constexpr int TPN = K / 8;            // lanes per row (ushort8 each)
        constexpr int GROUPS = 256 / TPN;     // concurrent rows per batch
        int g = tid / TPN, c8 = tid % TPN;
        const ushort8* hp = (const ushort8*)h + c8;
#pragma unroll
        for (int b = 0; b < BM / GROUPS; ++b) {
            int n = rowbase + b * GROUPS + g;
            int nn = (n < M) ? n : (M - 1);   // pad rows duplicate last node
            float acc[8];
            ushort8 s0 = hp[(size_t)nn * TPN];
#pragma unroll
            for (int j = 0; j < 8; j++) acc[j] = bf2f(s0[j]);
            int p = rowptr[nn], end = rowptr[nn + 1];
            for (; p + 8 <= end; p += 8) {
                int j0 = csr[p],     j1 = csr[p + 1], j2 = csr[p + 2], j3 = csr[p + 3];
                int j4 = csr[p + 4], j5 = csr[p + 5], j6 = csr[p + 6], j7 = csr[p + 7];
                ushort8 v0 = hp[(size_t)j0 * TPN];
                ushort8 v1 = hp[(size_t)j1 * TPN];
                ushort8 v2 = hp[(size_t)j2 * TPN];
                ushort8 v3 = hp[(size_t)j3 * TPN];
                ushort8 v4 = hp[(size_t)j4 * TPN];
                ushort8 v5 = hp[(size_t)j5 * TPN];
                ushort8 v6 = hp[(size_t)j6 * TPN];
                ushort8 v7 = hp[(size_t)j7 * TPN];
#pragma unroll
                for (int j = 0; j < 8; j++)
                    acc[j] += ((bf2f(v0[j]) + bf2f(v1[j])) + (bf2f(v2[j]) + bf2f(v3[j]))) +
                              ((bf2f(v4[j]) + bf2f(v5[j])) + (bf2f(v6[j]) + bf2f(v7[j])));
            }
            for (; p + 4 <= end; p += 4) {
                int j0 = csr[p], j1 = csr[p + 1], j2 = csr[p + 2], j3 = csr[p + 3];
                ushort8 v0 = hp[(size_t)j0 * TPN];
                ushort8 v1 = hp[(size_t)j1 * TPN];
                ushort8 v2 = hp[(size_t)j2 * TPN];
                ushort8 v3 = hp[(size_t)j3 * TPN];
#pragma unroll
                for (int j = 0; j < 8; j++)
                    acc[j] += (bf2f(v0[j]) + bf2f(v1[j])) + (bf2f(v2[j]) + bf2f(v3[j]));
            }
            for (; p < end; ++p) {
                int jj = csr[p];
                ushort8 v = hp[(size_t)jj * TPN];
#pragma unroll
                for (int j = 0; j < 8; j++) acc[j] += bf2f(v[j]);
            }
            ushort8 o;
#pragma unroll
            for (int j = 0; j < 8; j++) o[j] = f2bf(acc[j]);
            int r = b * GROUPS + g;
            unsigned byte = (unsigned)r * AW + (unsigned)c8 * 16;
            byte ^= (unsigned)((r & 7) << 4);
            *(ushort8*)((char*)As + byte) = o;
        }
    }
    __syncthreads();

    // ---------------- phase 2: MFMA GEMM ----------------
    int wn = wave;                             // 4 waves = 4 col-panels of 64
    int rslot = lkc * 16 + (lr ^ (lkc << 2));
    // W staging (k0-invariant part): call i writes slots i*256+tid.
    // slot s: ntile=s>>6, kc=(s>>4)&3, rx=s&15 holds
    // W[ntile*16 + (rx^(kc<<2))][k0 + kc*8 ..+8]
    const unsigned short* wsrc[4];
    char* wdst[4];
#pragma unroll
    for (int i = 0; i < 4; i++) {
        int slot = i * 256 + tid;
        int ntile = slot >> 6, kc = (slot >> 4) & 3, rx = slot & 15;
        int wrow = ntile * 16 + (rx ^ (kc << 2));
        wsrc[i] = W + (size_t)wrow * K + kc * 8;
        wdst[i] = (char*)Ws + (size_t)(i * 256 + wave * 64) * 16;
    }

    floatx4 acc[4][4];
#pragma unroll
    for (int i = 0; i < 4; i++)
#pragma unroll
        for (int j = 0; j < 4; j++) acc[i][j] = (floatx4)(0.f);

#pragma unroll 2
    for (int k0 = 0; k0 < K; k0 += 32) {
#pragma unroll
        for (int i = 0; i < 4; i++) g2lds16(wsrc[i] + k0, wdst[i]);
        __syncthreads();

        short8 af[4], wf[4];
#pragma unroll
        for (int mt = 0; mt < 4; mt++) {
            unsigned abyte = (unsigned)(mt * 16 + lr) * AW + (unsigned)(k0 + lkc * 8) * 2;
            abyte ^= (unsigned)((lr & 7) << 4);
            af[mt] = *(const short8*)((const char*)As + abyte);
        }
#pragma unroll
        for (int nt = 0; nt < 4; nt++) wf[nt] = Ws[(wn * 4 + nt) * 64 + rslot];
#pragma unroll
        for (int mt = 0; mt < 4; mt++)
#pragma unroll
            for (int nt = 0; nt < 4; nt++)
                acc[mt][nt] = __builtin_amdgcn_mfma_f32_16x16x32_bf16(
                    af[mt], wf[nt], acc[mt][nt], 0, 0, 0);
        __syncthreads();
    }

    // C/D layout: col=lane&15, row=(lane>>4)*4+reg
#pragma unroll
    for (int mt = 0; mt < 4; mt++) {
#pragma unroll
        for (int reg = 0; reg < 4; reg++) {
            int row = rowbase + mt * 16 + lkc * 4 + reg;
            if (row >= M) continue;
#pragma unroll
            for (int nt = 0; nt < 4; nt++) {
                int col = wn * 64 + nt * 16 + lr;
                float v = acc[mt][nt][reg] + bias[col];
                out[(size_t)row * 256 + col] = f2bf(fmaxf(v, 0.f));
            }
        }
    }
}

// ------- fused mean-pool + MLP head: one block (256 thr) per graph ---------
__global__ __launch_bounds__(256) void pool_head(
    const unsigned short* __restrict__ h, const int* __restrict__ batch,
    const float* __restrict__ Wf1, const float* __restrict__ bf1,
    const float* __restrict__ Wf2, const float* __restrict__ bf2,
    float* __restrict__ out) {
    __shared__ float hg[256];
    __shared__ float hid[128];
    int g = blockIdx.x;
    int t = threadIdx.x;
    int lo = 0, hi = N_NODES;
    while (lo < hi) { int m = (lo + hi) >> 1; if (batch[m] < g) lo = m + 1; else hi = m; }
    int start = lo;
    lo = 0; hi = N_NODES;
    while (lo < hi) { int m = (lo + hi) >> 1; if (batch[m] < g + 1) lo = m + 1; else hi = m; }
    int end = lo;
    float acc = 0.f;
    for (int r = start; r < end; ++r) acc += bf2f(h[(size_t)r * 256 + t]);
    hg[t] = acc / fmaxf((float)(end - start), 1.0f);
    __syncthreads();
    if (t < 128) {
        float a1 = bf1[t];
        for (int c = 0; c < 256; c++) a1 += hg[c] * Wf1[t * 256 + c];
        hid[t] = fmaxf(a1, 0.f);
    }
    __syncthreads();
    if (t < 10) {
        float a = bf2[t];
        for (int j = 0; j < 128; j++) a += hid[j] * Wf2[t * 128 + j];
        out[g * 10 + t] = a;
    }
}

extern "C" void kernel_launch(void* const* d_in, const int* in_sizes, int n_in,
                              void* d_out, int out_size, void* d_ws, size_t ws_size,
                              hipStream_t stream) {
    const float* x   = (const float*)d_in[0];
    const int*  edge = (const int*)d_in[1];
    const int*  batch= (const int*)d_in[2];
    const float* W1  = (const float*)d_in[3];
    const float* b1  = (const float*)d_in[4];
    const float* W2  = (const float*)d_in[5];
    const float* b2  = (const float*)d_in[6];
    const float* W3  = (const float*)d_in[7];
    const float* b3  = (const float*)d_in[8];
    const float* Wf1 = (const float*)d_in[9];
    const float* bf1 = (const float*)d_in[10];
    const float* Wf2 = (const float*)d_in[11];
    const float* bf2 = (const float*)d_in[12];
    const int* src = edge;
    const int* dst = edge + N_EDGES;

    char* wsb = (char*)d_ws;
    size_t off = 0;
    auto alloc = [&](size_t bytes) { void* p = wsb + off; off += (bytes + 255) & ~(size_t)255; return p; };
    unsigned short* x_bf  = (unsigned short*)alloc((size_t)N_NODES * 128 * 2);
    unsigned short* hA_bf = (unsigned short*)alloc((size_t)N_NODES * 256 * 2);
    unsigned short* hB_bf = (unsigned short*)alloc((size_t)N_NODES * 256 * 2);
    unsigned short* W1bf  = (unsigned short*)alloc(256 * 128 * 2);
    unsigned short* W2bf  = (unsigned short*)alloc(256 * 256 * 2);
    unsigned short* W3bf  = (unsigned short*)alloc(256 * 256 * 2);
    int* rowptr   = (int*)alloc((N_NODES + 4) * 4);
    int* cursor   = (int*)alloc(N_NODES * 4);
    int* deg      = (int*)alloc(N_NODES * 4);
    int* csr      = (int*)alloc(N_EDGES * 4);
    int* blocksum = (int*)alloc(64 * 4);

    const int NB_SCAN = (N_NODES + 1023) / 1024;  // 49

    // ---- CSR build (by dst) ----
    hipMemsetAsync(deg, 0, N_NODES * sizeof(int), stream);
    deg_hist<<<(N_EDGES + 255) / 256, 256, 0, stream>>>(dst, deg);
    scan1<<<NB_SCAN, 1024, 0, stream>>>(deg, rowptr, blocksum);
    scan2<<<1, 64, 0, stream>>>(blocksum, NB_SCAN);
    scan3<<<NB_SCAN, 1024, 0, stream>>>(rowptr, blocksum, cursor);
    scatter_csr<<<(N_EDGES + 255) / 256, 256, 0, stream>>>(src, dst, cursor, csr);

    // ---- converts (x + all weights, one launch) ----
    convert_all<<<(1640960 + 255) / 256, 256, 0, stream>>>(x, W1, W2, W3, x_bf, W1bf, W2bf, W3bf);

    const int NB_FUSED = (N_NODES + 63) / 64;  // 782

    // ---- fused layers: gather + GEMM in one kernel (no agg round-trip) ----
    gin_fused<128><<<NB_FUSED, 256, 0, stream>>>(x_bf,  rowptr, csr, W1bf, b1, hA_bf, N_NODES);
    gin_fused<256><<<NB_FUSED, 256, 0, stream>>>(hA_bf, rowptr, csr, W2bf, b2, hB_bf, N_NODES);
    gin_fused<256><<<NB_FUSED, 256, 0, stream>>>(hB_bf, rowptr, csr, W3bf, b3, hA_bf, N_NODES);

    // ---- fused mean pool + head ----
    pool_head<<<N_GRAPHS, 256, 0, stream>>>(hA_bf, batch, Wf1, bf1, Wf2, bf2, (float*)d_out);
}

// Round 2
// 454.937 us; speedup vs baseline: 1.0714x; 1.0714x over previous
//
#include <hip/hip_runtime.h>

#define N_NODES 50000
#define N_GRAPHS 512
#define N_EDGES 800000

typedef __attribute__((ext_vector_type(8))) short short8;
typedef __attribute__((ext_vector_type(8))) unsigned short ushort8;
typedef __attribute__((ext_vector_type(4))) float floatx4;

__device__ __forceinline__ float bf2f(unsigned short u) {
    union { unsigned int i; float f; } c;
    c.i = ((unsigned int)u) << 16;
    return c.f;
}
__device__ __forceinline__ unsigned short f2bf(float f) {
    union { float f; unsigned int i; } c;
    c.f = f;
    unsigned int u = c.i;
    return (unsigned short)((u + 0x7fffu + ((u >> 16) & 1u)) >> 16);
}

// ---------------- fused converts: x (1.6M float4) + W1/W2/W3 (40960) -------
__global__ void convert_all(const float* __restrict__ x, const float* __restrict__ W1,
                            const float* __restrict__ W2, const float* __restrict__ W3,
                            unsigned short* __restrict__ xo, unsigned short* __restrict__ o1,
                            unsigned short* __restrict__ o2, unsigned short* __restrict__ o3) {
    int i = blockIdx.x * blockDim.x + threadIdx.x;  // 0..1640959
    const float* src; unsigned short* dst; int base;
    if (i < 1600000)      { src = x;  dst = xo; base = i; }
    else {
        int j = i - 1600000;
        if (j < 8192)       { src = W1; dst = o1; base = j; }
        else if (j < 24576) { src = W2; dst = o2; base = j - 8192; }
        else if (j < 40960) { src = W3; dst = o3; base = j - 24576; }
        else return;
    }
    float4 v = ((const float4*)src)[base];
    ushort4 o;
    o.x = f2bf(v.x); o.y = f2bf(v.y); o.z = f2bf(v.z); o.w = f2bf(v.w);
    ((ushort4*)dst)[base] = o;
}

// ---------------- CSR build ----------------
__global__ void deg_hist(const int* __restrict__ dst, int* __restrict__ deg) {
    int e = blockIdx.x * blockDim.x + threadIdx.x;
    if (e < N_EDGES) atomicAdd(&deg[dst[e]], 1);
}

__global__ __launch_bounds__(1024) void scan1(const int* __restrict__ deg,
                                              int* __restrict__ rowptr,
                                              int* __restrict__ blocksum) {
    __shared__ int s[1024];
    int t = threadIdx.x;
    int i = blockIdx.x * 1024 + t;
    int v = (i < N_NODES) ? deg[i] : 0;
    s[t] = v;
    __syncthreads();
    for (int off = 1; off < 1024; off <<= 1) {
        int add = (t >= off) ? s[t - off] : 0;
        __syncthreads();
        s[t] += add;
        __syncthreads();
    }
    if (i < N_NODES) rowptr[i] = s[t] - v;  // exclusive
    if (t == 1023) blocksum[blockIdx.x] = s[t];
}

// wave-parallel exclusive scan of block sums (nb <= 64)
__global__ void scan2(int* __restrict__ blocksum, int nb) {
    int t = threadIdx.x;  // 64 threads, one wave
    int orig = (t < nb) ? blocksum[t] : 0;
    int v = orig;
    for (int off = 1; off < 64; off <<= 1) {
        int u = __shfl_up(v, off, 64);
        if (t >= off) v += u;
    }
    if (t < nb) blocksum[t] = v - orig;  // exclusive
}

__global__ void scan3(int* __restrict__ rowptr, const int* __restrict__ blocksum,
                      int* __restrict__ cursor) {
    int i = blockIdx.x * blockDim.x + threadIdx.x;
    if (i < N_NODES) {
        int v = rowptr[i] + blocksum[i >> 10];
        rowptr[i] = v;
        cursor[i] = v;
    }
    if (i == 0) rowptr[N_NODES] = N_EDGES;
}

__global__ void scatter_csr(const int* __restrict__ src, const int* __restrict__ dst,
                            int* __restrict__ cursor, int* __restrict__ csr) {
    int e = blockIdx.x * blockDim.x + threadIdx.x;
    if (e < N_EDGES) {
        int pos = atomicAdd(&cursor[dst[e]], 1);
        csr[pos] = src[e];
    }
}

// ---- FUSED gather + MFMA GEMM (v2: MLP-restored) --------------------------
// R1 post-mortem: BM=64 + 48KB LDS capped residency at 12 waves/CU and the
// gather (latency-bound random 512B reads) ran at 2.0 TB/s vs 3.6 standalone
// — bandwidth tracked resident waves exactly. v2 restores parallelism:
//  * BM=32 -> grid 1563 (6.1 blocks/CU), A-tile 16KB (K=256) / 8KB (K=128)
//  * W fragments read DIRECTLY from global (W <= 128KB, L2-hot across all
//    blocks; lanes {lr equal, lkc 0..3} form 64B-contiguous lines). Deletes
//    the Ws LDS buffer AND every K-loop __syncthreads: after the one
//    post-gather barrier the GEMM is barrier-free, so waves drift and MFMA
//    of one block overlaps gather loads of its CU-mates.
// A-tile swizzle unchanged: byte ^= (row&7)<<4 (2-way residual, free).
template <int K>
__global__ __launch_bounds__(256, 5) void gin_fused(
    const unsigned short* __restrict__ h, const int* __restrict__ rowptr,
    const int* __restrict__ csr, const unsigned short* __restrict__ W,
    const float* __restrict__ bias, unsigned short* __restrict__ out, int M) {
    constexpr int BM = 32;
    constexpr int AW = K * 2;                 // bytes per A row
    __shared__ unsigned short As[BM * K];     // 16 KB (K=256) / 8 KB (K=128)

    int tid = threadIdx.x;
    int wave = tid >> 6, lane = tid & 63;
    int lkc = lane >> 4, lr = lane & 15;
    int rowbase = blockIdx.x * BM;

    // ---------------- phase 1: gather into LDS A-tile ----------------
    {
        constexpr int TPN = K / 8;            // lanes per row (ushort8 each)
        constexpr int GROUPS = 256 / TPN;     // concurrent rows per batch
        int g = tid / TPN, c8 = tid % TPN;
        const ushort8* hp = (const ushort8*)h + c8;
#pragma unroll
        for (int b = 0; b < BM / GROUPS; ++b) {
            int n = rowbase + b * GROUPS + g;
            int nn = (n < M) ? n : (M - 1);   // pad rows duplicate last node
            float acc[8];
            ushort8 s0 = hp[(size_t)nn * TPN];
#pragma unroll
            for (int j = 0; j < 8; j++) acc[j] = bf2f(s0[j]);
            int p = rowptr[nn], end = rowptr[nn + 1];
            for (; p + 8 <= end; p += 8) {
                int j0 = csr[p],     j1 = csr[p + 1], j2 = csr[p + 2], j3 = csr[p + 3];
                int j4 = csr[p + 4], j5 = csr[p + 5], j6 = csr[p + 6], j7 = csr[p + 7];
                ushort8 v0 = hp[(size_t)j0 * TPN];
                ushort8 v1 = hp[(size_t)j1 * TPN];
                ushort8 v2 = hp[(size_t)j2 * TPN];
                ushort8 v3 = hp[(size_t)j3 * TPN];
                ushort8 v4 = hp[(size_t)j4 * TPN];
                ushort8 v5 = hp[(size_t)j5 * TPN];
                ushort8 v6 = hp[(size_t)j6 * TPN];
                ushort8 v7 = hp[(size_t)j7 * TPN];
#pragma unroll
                for (int j = 0; j < 8; j++)
                    acc[j] += ((bf2f(v0[j]) + bf2f(v1[j])) + (bf2f(v2[j]) + bf2f(v3[j]))) +
                              ((bf2f(v4[j]) + bf2f(v5[j])) + (bf2f(v6[j]) + bf2f(v7[j])));
            }
            for (; p + 4 <= end; p += 4) {
                int j0 = csr[p], j1 = csr[p + 1], j2 = csr[p + 2], j3 = csr[p + 3];
                ushort8 v0 = hp[(size_t)j0 * TPN];
                ushort8 v1 = hp[(size_t)j1 * TPN];
                ushort8 v2 = hp[(size_t)j2 * TPN];
                ushort8 v3 = hp[(size_t)j3 * TPN];
#pragma unroll
                for (int j = 0; j < 8; j++)
                    acc[j] += (bf2f(v0[j]) + bf2f(v1[j])) + (bf2f(v2[j]) + bf2f(v3[j]));
            }
            for (; p < end; ++p) {
                int jj = csr[p];
                ushort8 v = hp[(size_t)jj * TPN];
#pragma unroll
                for (int j = 0; j < 8; j++) acc[j] += bf2f(v[j]);
            }
            ushort8 o;
#pragma unroll
            for (int j = 0; j < 8; j++) o[j] = f2bf(acc[j]);
            int r = b * GROUPS + g;
            unsigned byte = (unsigned)r * AW + (unsigned)c8 * 16;
            byte ^= (unsigned)((r & 7) << 4);
            *(ushort8*)((char*)As + byte) = o;
        }
    }
    __syncthreads();

    // ---------------- phase 2: MFMA GEMM (barrier-free) ----------------
    // wave wn covers output cols [wn*64, wn*64+64); rows 0..31 (mt=0..1).
    // B fragment (direct global): wf[nt] = W[(wn*4+nt)*16 + lr][k0+lkc*8 ..+8]
    int wn = wave;
    const short8* wp[4];
#pragma unroll
    for (int nt = 0; nt < 4; nt++)
        wp[nt] = (const short8*)(W + (size_t)(wn * 64 + nt * 16 + lr) * K) + lkc;

    floatx4 acc[2][4];
#pragma unroll
    for (int i = 0; i < 2; i++)
#pragma unroll
        for (int j = 0; j < 4; j++) acc[i][j] = (floatx4)(0.f);

#pragma unroll 2
    for (int k0 = 0; k0 < K; k0 += 32) {
        short8 af[2], wf[4];
#pragma unroll
        for (int nt = 0; nt < 4; nt++) wf[nt] = wp[nt][k0 >> 3];
#pragma unroll
        for (int mt = 0; mt < 2; mt++) {
            unsigned abyte = (unsigned)(mt * 16 + lr) * AW + (unsigned)(k0 + lkc * 8) * 2;
            abyte ^= (unsigned)((lr & 7) << 4);
            af[mt] = *(const short8*)((const char*)As + abyte);
        }
#pragma unroll
        for (int mt = 0; mt < 2; mt++)
#pragma unroll
            for (int nt = 0; nt < 4; nt++)
                acc[mt][nt] = __builtin_amdgcn_mfma_f32_16x16x32_bf16(
                    af[mt], wf[nt], acc[mt][nt], 0, 0, 0);
    }

    // C/D layout: col=lane&15, row=(lane>>4)*4+reg
#pragma unroll
    for (int mt = 0; mt < 2; mt++) {
#pragma unroll
        for (int reg = 0; reg < 4; reg++) {
            int row = rowbase + mt * 16 + lkc * 4 + reg;
            if (row >= M) continue;
#pragma unroll
            for (int nt = 0; nt < 4; nt++) {
                int col = wn * 64 + nt * 16 + lr;
                float v = acc[mt][nt][reg] + bias[col];
                out[(size_t)row * 256 + col] = f2bf(fmaxf(v, 0.f));
            }
        }
    }
}

// ------- fused mean-pool + MLP head: one block (256 thr) per graph ---------
__global__ __launch_bounds__(256) void pool_head(
    const unsigned short* __restrict__ h, const int* __restrict__ batch,
    const float* __restrict__ Wf1, const float* __restrict__ bf1,
    const float* __restrict__ Wf2, const float* __restrict__ bf2,
    float* __restrict__ out) {
    __shared__ float hg[256];
    __shared__ float hid[128];
    int g = blockIdx.x;
    int t = threadIdx.x;
    int lo = 0, hi = N_NODES;
    while (lo < hi) { int m = (lo + hi) >> 1; if (batch[m] < g) lo = m + 1; else hi = m; }
    int start = lo;
    lo = 0; hi = N_NODES;
    while (lo < hi) { int m = (lo + hi) >> 1; if (batch[m] < g + 1) lo = m + 1; else hi = m; }
    int end = lo;
    float acc = 0.f;
    for (int r = start; r < end; ++r) acc += bf2f(h[(size_t)r * 256 + t]);
    hg[t] = acc / fmaxf((float)(end - start), 1.0f);
    __syncthreads();
    if (t < 128) {
        float a1 = bf1[t];
        for (int c = 0; c < 256; c++) a1 += hg[c] * Wf1[t * 256 + c];
        hid[t] = fmaxf(a1, 0.f);
    }
    __syncthreads();
    if (t < 10) {
        float a = bf2[t];
        for (int j = 0; j < 128; j++) a += hid[j] * Wf2[t * 128 + j];
        out[g * 10 + t] = a;
    }
}

extern "C" void kernel_launch(void* const* d_in, const int* in_sizes, int n_in,
                              void* d_out, int out_size, void* d_ws, size_t ws_size,
                              hipStream_t stream) {
    const float* x   = (const float*)d_in[0];
    const int*  edge = (const int*)d_in[1];
    const int*  batch= (const int*)d_in[2];
    const float* W1  = (const float*)d_in[3];
    const float* b1  = (const float*)d_in[4];
    const float* W2  = (const float*)d_in[5];
    const float* b2  = (const float*)d_in[6];
    const float* W3  = (const float*)d_in[7];
    const float* b3  = (const float*)d_in[8];
    const float* Wf1 = (const float*)d_in[9];
    const float* bf1 = (const float*)d_in[10];
    const float* Wf2 = (const float*)d_in[11];
    const float* bf2 = (const float*)d_in[12];
    const int* src = edge;
    const int* dst = edge + N_EDGES;

    char* wsb = (char*)d_ws;
    size_t off = 0;
    auto alloc = [&](size_t bytes) { void* p = wsb + off; off += (bytes + 255) & ~(size_t)255; return p; };
    unsigned short* x_bf  = (unsigned short*)alloc((size_t)N_NODES * 128 * 2);
    unsigned short* hA_bf = (unsigned short*)alloc((size_t)N_NODES * 256 * 2);
    unsigned short* hB_bf = (unsigned short*)alloc((size_t)N_NODES * 256 * 2);
    unsigned short* W1bf  = (unsigned short*)alloc(256 * 128 * 2);
    unsigned short* W2bf  = (unsigned short*)alloc(256 * 256 * 2);
    unsigned short* W3bf  = (unsigned short*)alloc(256 * 256 * 2);
    int* rowptr   = (int*)alloc((N_NODES + 4) * 4);
    int* cursor   = (int*)alloc(N_NODES * 4);
    int* deg      = (int*)alloc(N_NODES * 4);
    int* csr      = (int*)alloc(N_EDGES * 4);
    int* blocksum = (int*)alloc(64 * 4);

    const int NB_SCAN = (N_NODES + 1023) / 1024;  // 49

    // ---- CSR build (by dst) ----
    hipMemsetAsync(deg, 0, N_NODES * sizeof(int), stream);
    deg_hist<<<(N_EDGES + 255) / 256, 256, 0, stream>>>(dst, deg);
    scan1<<<NB_SCAN, 1024, 0, stream>>>(deg, rowptr, blocksum);
    scan2<<<1, 64, 0, stream>>>(blocksum, NB_SCAN);
    scan3<<<NB_SCAN, 1024, 0, stream>>>(rowptr, blocksum, cursor);
    scatter_csr<<<(N_EDGES + 255) / 256, 256, 0, stream>>>(src, dst, cursor, csr);

    // ---- converts (x + all weights, one launch) ----
    convert_all<<<(1640960 + 255) / 256, 256, 0, stream>>>(x, W1, W2, W3, x_bf, W1bf, W2bf, W3bf);

    const int NB_FUSED = (N_NODES + 31) / 32;  // 1563

    // ---- fused layers: gather + GEMM in one kernel (no agg round-trip) ----
    gin_fused<128><<<NB_FUSED, 256, 0, stream>>>(x_bf,  rowptr, csr, W1bf, b1, hA_bf, N_NODES);
    gin_fused<256><<<NB_FUSED, 256, 0, stream>>>(hA_bf, rowptr, csr, W2bf, b2, hB_bf, N_NODES);
    gin_fused<256><<<NB_FUSED, 256, 0, stream>>>(hB_bf, rowptr, csr, W3bf, b3, hA_bf, N_NODES);

    // ---- fused mean pool + head ----
    pool_head<<<N_GRAPHS, 256, 0, stream>>>(hA_bf, batch, Wf1, bf1, Wf2, bf2, (float*)d_out);
}